// Round 4
// baseline (105.189 us; speedup 1.0000x reference)
//
#include <hip/hip_runtime.h>

// ---------------------------------------------------------------------------
// GCNArchEmbedder on MI355X — gather-table formulation, v2c.
//
// Algebra: out[r] = sum_t cnt_t * relu(X[a_t] + X[b_t]) @ (0.25*W2)
// Only 38 distinct X rows (36 op-pair combos + 2 init rows) -> 38*38 = 1444
// distinct relu-pair rows. Prep precomputes
//     G[q=a*38+b][f] = sum_k 0.25*relu(X[a][k]+X[b][k]) * W2[k][f]
// (1444 x 128 fp32 = 739 KB, L2-resident). Main is a pure 4-way gather +
// weighted sum per row (write-BW bound, ~36 MB HBM).
//
// v2: prep 1024 threads / 32 G-rows / single-pass G loop / sV LDS overlay;
//     main nt-stores so the 32 MB output stream doesn't evict G from L2.
// v2b: fix smisc arena sizing (528 floats).
// v2c: nontemporal loads need clang ext-vector types, not HIP int4.
// ---------------------------------------------------------------------------

typedef __attribute__((ext_vector_type(4))) float f32x4;
typedef __attribute__((ext_vector_type(4))) int   i32x4;

#define NSYM 38
#define NPAIR (NSYM * NSYM)          // 1444
#define G_ROWS_PER_BLOCK 32
#define PREP_BLOCKS ((NPAIR + G_ROWS_PER_BLOCK - 1) / G_ROWS_PER_BLOCK)  // 46

__global__ __launch_bounds__(1024) void prep_kernel(
    const float* __restrict__ init_emb,   // 2 x 96
    const float* __restrict__ op_emb,     // 8 x 48 (rows 0..5 used)
    const float* __restrict__ wx,         // 96 x 48
    const float* __restrict__ xb,         // 48
    const float* __restrict__ w1,         // 48 x 128
    const float* __restrict__ w2,         // 128 x 128
    float* __restrict__ G)                // out: 1444 x 128
{
  // Single aliased LDS arena (54,976 B):
  //   [0      ,18432) swx   (96x48 f)    -- dead after U
  //   [18432  ,43008) sw1   (48x128 f)   -- dead after R
  //   [43008  ,45120) smisc (528 f: op 0..287, init 288..479, xb 480..527)
  //   [45120  ,47808) sU    (14x48 f)
  //   [47808  ,54976) sR    (14x128 f)
  //   sV (32x128 f = 16384 B) overlays [0,16384) after the post-R barrier.
  __shared__ __align__(16) char smem[54976];
  float* swx   = (float*)smem;
  float* sw1   = (float*)(smem + 18432);
  float* smisc = (float*)(smem + 43008);
  float* sU    = (float*)(smem + 45120);
  float* sR    = (float*)(smem + 47808);
  float* sV    = (float*)smem;            // overlay, valid after R barrier

  const int tid = threadIdx.x;
  const int qbase = blockIdx.x * G_ROWS_PER_BLOCK;

  for (int i = tid; i < 96 * 48; i += 1024) swx[i] = wx[i];
  for (int i = tid; i < 48 * 128; i += 1024) sw1[i] = w1[i];
  if (tid < 288) smisc[tid] = op_emb[tid];
  else if (tid < 480) smisc[tid] = init_emb[tid - 288];
  else if (tid < 528) smisc[tid] = xb[tid - 480];
  __syncthreads();

  const float* sob   = smisc;
  const float* sinit = smisc + 288;
  const float* sxb   = smisc + 480;

  // U rows: 0..5 = xb + op@Wx[0:48]; 6..11 = op@Wx[48:96]; 12..13 = xb + init@Wx
  if (tid < 14 * 48) {
    int row = tid / 48, k = tid - row * 48;
    float s;
    if (row < 6) {
      s = sxb[k];
      for (int j = 0; j < 48; ++j) s += sob[row * 48 + j] * swx[j * 48 + k];
    } else if (row < 12) {
      s = 0.f;
      for (int j = 0; j < 48; ++j) s += sob[(row - 6) * 48 + j] * swx[(48 + j) * 48 + k];
    } else {
      s = sxb[k];
      for (int j = 0; j < 96; ++j) s += sinit[(row - 12) * 96 + j] * swx[j * 48 + k];
    }
    sU[row * 48 + k] = s;
  }
  __syncthreads();

  // R = U @ W1   (rows 0..5 = P1', 6..11 = P2, 12..13 = Z)
  for (int idx = tid; idx < 14 * 128; idx += 1024) {
    int row = idx >> 7, f = idx & 127;
    float s = 0.f;
    for (int k = 0; k < 48; ++k) s += sU[row * 48 + k] * sw1[k * 128 + f];
    sR[idx] = s;
  }
  __syncthreads();   // after this, swx/sw1 are dead -> sV overlay is safe

  // sV[i][f] = 0.25 * relu(T[x][f] + T[y][f]),  q = qbase+i, x=q/38, y=q%38
  // T[s<36] = R[s/6] + R[6 + s%6];  T[36]=R[12], T[37]=R[13]
  for (int idx = tid; idx < G_ROWS_PER_BLOCK * 128; idx += 1024) {
    int i = idx >> 7, f = idx & 127;
    int q = qbase + i; if (q > NPAIR - 1) q = NPAIR - 1;   // clamp (store guarded)
    int x = q / NSYM, y = q - x * NSYM;
    float tx, ty;
    if (x < 36) { int o1 = x / 6, o2 = x - o1 * 6; tx = sR[o1 * 128 + f] + sR[(6 + o2) * 128 + f]; }
    else        { tx = sR[(x - 24) * 128 + f]; }
    if (y < 36) { int o1 = y / 6, o2 = y - o1 * 6; ty = sR[o1 * 128 + f] + sR[(6 + o2) * 128 + f]; }
    else        { ty = sR[(y - 24) * 128 + f]; }
    sV[idx] = 0.25f * fmaxf(tx + ty, 0.f);
  }
  __syncthreads();

  // G rows = sV @ W2. thread -> (slot, f-quad), single pass.
  const int fq   = tid & 31;        // f = fq*4
  const int slot = tid >> 5;        // 0..31
  f32x4 acc = {0.f, 0.f, 0.f, 0.f};
  const float* w2p = w2 + fq * 4;   // L2-hot after first block
  const float* vp  = sV + slot * 128;
#pragma unroll 4
  for (int k = 0; k < 128; ++k) {
    f32x4 w = *(const f32x4*)(w2p + k * 128);   // coalesced 512B/wave
    acc += vp[k] * w;                            // LDS broadcast
  }
  const int q = qbase + slot;
  if (q < NPAIR) *(f32x4*)(G + q * 128 + fq * 4) = acc;
}

// Main: per row decode 4 (pair, count) descriptors, then 4 coalesced 512B
// gathers from G + weighted sum + 1 coalesced 512B nontemporal store.
__global__ __launch_bounds__(256, 4) void main_kernel(
    const int* __restrict__ archs,   // 65536 rows x 16 ints (8 prev, 8 op)
    const float* __restrict__ G,     // 1444 x 128
    float* __restrict__ out)         // 65536 x 128 fp32
{
  __shared__ int   soff[64][4];   // float-index of G row * 128
  __shared__ float scf[64][4];

  const int tid = threadIdx.x;
  const int rbase = blockIdx.x * 64;

  if (tid < 64) {
    const i32x4* ar = (const i32x4*)(archs + (rbase + tid) * 16);
    i32x4 pv0 = __builtin_nontemporal_load(ar);       // prev[0..3]
    i32x4 pv1 = __builtin_nontemporal_load(ar + 1);   // prev[4..7]
    i32x4 op0 = __builtin_nontemporal_load(ar + 2);   // op[0..3]
    i32x4 op1 = __builtin_nontemporal_load(ar + 3);   // op[4..7]

    const int sp0 = op0.x * 6 + op0.y;
    const int sp1 = op0.z * 6 + op0.w;
    const int sp2 = op1.x * 6 + op1.y;
    const int sp3 = op1.z * 6 + op1.w;

    int prev[8] = {pv0.x, pv0.y, pv0.z, pv0.w, pv1.x, pv1.y, pv1.z, pv1.w};
#pragma unroll
    for (int t = 0; t < 4; ++t) {
      int pa = prev[2 * t], pb = prev[2 * t + 1];
      int a = (pa == 0) ? 36 : (pa == 1) ? 37 : (pa == 2) ? sp0
            : (pa == 3) ? sp1 : (pa == 4) ? sp2 : sp3;
      int b = (pb == 0) ? 36 : (pb == 1) ? 37 : (pb == 2) ? sp0
            : (pb == 3) ? sp1 : (pb == 4) ? sp2 : sp3;
      int c = 0;
#pragma unroll
      for (int e = 0; e < 8; ++e) c += (prev[e] == t + 2) ? 1 : 0;
      soff[tid][t] = (a * NSYM + b) * 128;
      scf[tid][t]  = (float)c;
    }
  }
  __syncthreads();

  const int lane32 = tid & 31;
  const int grp    = tid >> 5;     // 8 groups x 8 rows
#pragma unroll
  for (int rr = 0; rr < 8; ++rr) {
    const int row = grp * 8 + rr;
    int4  o4 = *(const int4*)&soff[row][0];   // broadcast LDS reads
    f32x4 c4 = *(const f32x4*)&scf[row][0];
    f32x4 v0 = *(const f32x4*)(G + o4.x + lane32 * 4);   // L2-hit gathers
    f32x4 v1 = *(const f32x4*)(G + o4.y + lane32 * 4);
    f32x4 v2 = *(const f32x4*)(G + o4.z + lane32 * 4);
    f32x4 v3 = *(const f32x4*)(G + o4.w + lane32 * 4);
    f32x4 acc = c4.x * v0;
    acc += c4.y * v1;
    acc += c4.z * v2;
    acc += c4.w * v3;
    // nt store: don't let the 32 MB output stream evict G from L2
    __builtin_nontemporal_store(acc, (f32x4*)(out + (rbase + row) * 128 + lane32 * 4));
  }
}

extern "C" void kernel_launch(void* const* d_in, const int* in_sizes, int n_in,
                              void* d_out, int out_size, void* d_ws, size_t ws_size,
                              hipStream_t stream) {
  const int*   archs  = (const int*)d_in[0];
  const float* init_e = (const float*)d_in[1];
  const float* op_e   = (const float*)d_in[2];
  const float* wx     = (const float*)d_in[3];
  const float* xb     = (const float*)d_in[4];
  const float* w1     = (const float*)d_in[5];
  const float* w2     = (const float*)d_in[6];

  float* G = (float*)d_ws;   // 1444 * 128 * 4 = 739,328 bytes

  prep_kernel<<<PREP_BLOCKS, 1024, 0, stream>>>(init_e, op_e, wx, xb, w1, w2, G);
  main_kernel<<<1024, 256, 0, stream>>>(archs, G, (float*)d_out);
}

// Round 5
// 100.328 us; speedup vs baseline: 1.0484x; 1.0484x over previous
//
#include <hip/hip_runtime.h>

// ---------------------------------------------------------------------------
// GCNArchEmbedder on MI355X — gather-table formulation, v3 (v1 revert + 1-pass G).
//
// Algebra: out[r] = sum_t cnt_t * relu(X[a_t] + X[b_t]) @ (0.25*W2)
// Only 38 distinct X rows (36 op-pair combos + 2 init rows) -> 38*38 = 1444
// distinct relu-pair rows. Prep precomputes
//     G[q=a*38+b][f] = sum_k 0.25*relu(X[a][k]+X[b][k]) * W2[k][f]
// (1444 x 128 fp32 = 739 KB, L2/L3-resident). Main is a pure 4-way gather +
// weighted sum per row (write-BW bound, ~36 MB HBM).
//
// v2/v2c lesson (105.2 us, +7 vs v1): nontemporal stores REGRESS — they
// bypass the 256 MB L3, forcing synchronous HBM writes; plain stores let
// L3 absorb the 32 MB output stream. Reverted. Prep 1024-thread/55KB-LDS
// restructure also reverted (unproven, suspected slower).
// v3 = v1 with prep at 512 threads so the G loop is single-pass.
// ---------------------------------------------------------------------------

typedef __attribute__((ext_vector_type(4))) float f32x4;

#define NSYM 38
#define NPAIR (NSYM * NSYM)          // 1444
#define G_ROWS_PER_BLOCK 16
#define PREP_BLOCKS ((NPAIR + G_ROWS_PER_BLOCK - 1) / G_ROWS_PER_BLOCK)  // 91

__global__ __launch_bounds__(512) void prep_kernel(
    const float* __restrict__ init_emb,   // 2 x 96
    const float* __restrict__ op_emb,     // 8 x 48 (rows 0..5 used)
    const float* __restrict__ wx,         // 96 x 48
    const float* __restrict__ xb,         // 48
    const float* __restrict__ w1,         // 48 x 128
    const float* __restrict__ w2,         // 128 x 128
    float* __restrict__ G)                // out: 1444 x 128
{
  __shared__ float swx[96 * 48];    // 18 KB
  __shared__ float sw1[48 * 128];   // 24 KB
  __shared__ float smisc[6 * 48 + 2 * 96 + 48];
  __shared__ float sU[14][48];
  __shared__ float sR[14 * 128];    // rows 0..5 = P1', 6..11 = P2, 12..13 = Z
  __shared__ float sV[16][128];     // 0.25*relu(Tx+Ty) for this block's rows

  const int tid = threadIdx.x;
  const int qbase = blockIdx.x * G_ROWS_PER_BLOCK;

  for (int i = tid; i < 96 * 48; i += 512) swx[i] = wx[i];
  for (int i = tid; i < 48 * 128; i += 512) sw1[i] = w1[i];
  if (tid < 288) smisc[tid] = op_emb[tid];
  if (tid < 192) smisc[288 + tid] = init_emb[tid];
  if (tid < 48)  smisc[480 + tid] = xb[tid];
  __syncthreads();

  const float* sob   = smisc;
  const float* sinit = smisc + 288;
  const float* sxb   = smisc + 480;

  // U rows: 0..5 = xb + op@Wx[0:48]; 6..11 = op@Wx[48:96]; 12..13 = xb + init@Wx
  for (int idx = tid; idx < 14 * 48; idx += 512) {
    int row = idx / 48, k = idx - row * 48;
    float s;
    if (row < 6) {
      s = sxb[k];
      for (int j = 0; j < 48; ++j) s += sob[row * 48 + j] * swx[j * 48 + k];
    } else if (row < 12) {
      s = 0.f;
      for (int j = 0; j < 48; ++j) s += sob[(row - 6) * 48 + j] * swx[(48 + j) * 48 + k];
    } else {
      s = sxb[k];
      for (int j = 0; j < 96; ++j) s += sinit[(row - 12) * 96 + j] * swx[j * 48 + k];
    }
    sU[row][k] = s;
  }
  __syncthreads();

  // R = U @ W1
  for (int idx = tid; idx < 14 * 128; idx += 512) {
    int row = idx >> 7, f = idx & 127;
    float s = 0.f;
    for (int k = 0; k < 48; ++k) s += sU[row][k] * sw1[k * 128 + f];
    sR[idx] = s;
  }
  __syncthreads();

  // sV[i][f] = 0.25 * relu(T[x][f] + T[y][f]),  q = qbase+i, x=q/38, y=q%38
  // T[s<36] = R[s/6] + R[6 + s%6];  T[36]=R[12], T[37]=R[13]
  for (int idx = tid; idx < 16 * 128; idx += 512) {
    int i = idx >> 7, f = idx & 127;
    int q = qbase + i; if (q > NPAIR - 1) q = NPAIR - 1;   // clamp (store guarded)
    int x = q / NSYM, y = q - x * NSYM;
    float tx, ty;
    if (x < 36) { int o1 = x / 6, o2 = x - o1 * 6; tx = sR[o1 * 128 + f] + sR[(6 + o2) * 128 + f]; }
    else        { tx = sR[(x - 24) * 128 + f]; }
    if (y < 36) { int o1 = y / 6, o2 = y - o1 * 6; ty = sR[o1 * 128 + f] + sR[(6 + o2) * 128 + f]; }
    else        { ty = sR[(y - 24) * 128 + f]; }
    sV[i][f] = 0.25f * fmaxf(tx + ty, 0.f);
  }
  __syncthreads();

  // G rows = sV @ W2. thread -> (slot, f-quad); single pass (512 = 16x32).
  const int fq   = tid & 31;        // f = fq*4
  const int slot = tid >> 5;        // 0..15
  f32x4 acc = {0.f, 0.f, 0.f, 0.f};
  const float* w2p = w2 + fq * 4;
  const float* vp  = &sV[slot][0];
#pragma unroll 4
  for (int k = 0; k < 128; ++k) {
    f32x4 w = *(const f32x4*)(w2p + k * 128);   // coalesced 512B/wave, L2-hot
    acc += vp[k] * w;                            // LDS broadcast
  }
  const int q = qbase + slot;
  if (q < NPAIR) *(f32x4*)(G + q * 128 + fq * 4) = acc;
}

// Main: per row decode 4 (pair, count) descriptors, then 4 coalesced 512B
// gathers from G + weighted sum + 1 coalesced 512B store (L3-absorbed).
__global__ __launch_bounds__(256, 4) void main_kernel(
    const int* __restrict__ archs,   // 65536 rows x 16 ints (8 prev, 8 op)
    const float* __restrict__ G,     // 1444 x 128
    float* __restrict__ out)         // 65536 x 128 fp32
{
  __shared__ int   soff[64][4];   // float-index of G row * 128
  __shared__ float scf[64][4];

  const int tid = threadIdx.x;
  const int rbase = blockIdx.x * 64;

  if (tid < 64) {
    const int* ar = archs + (rbase + tid) * 16;
    int4 pv0 = *(const int4*)(ar);
    int4 pv1 = *(const int4*)(ar + 4);
    int4 op0 = *(const int4*)(ar + 8);
    int4 op1 = *(const int4*)(ar + 12);

    const int sp0 = op0.x * 6 + op0.y;
    const int sp1 = op0.z * 6 + op0.w;
    const int sp2 = op1.x * 6 + op1.y;
    const int sp3 = op1.z * 6 + op1.w;

    int prev[8] = {pv0.x, pv0.y, pv0.z, pv0.w, pv1.x, pv1.y, pv1.z, pv1.w};
#pragma unroll
    for (int t = 0; t < 4; ++t) {
      int pa = prev[2 * t], pb = prev[2 * t + 1];
      int a = (pa == 0) ? 36 : (pa == 1) ? 37 : (pa == 2) ? sp0
            : (pa == 3) ? sp1 : (pa == 4) ? sp2 : sp3;
      int b = (pb == 0) ? 36 : (pb == 1) ? 37 : (pb == 2) ? sp0
            : (pb == 3) ? sp1 : (pb == 4) ? sp2 : sp3;
      int c = 0;
#pragma unroll
      for (int e = 0; e < 8; ++e) c += (prev[e] == t + 2) ? 1 : 0;
      soff[tid][t] = (a * NSYM + b) * 128;
      scf[tid][t]  = (float)c;
    }
  }
  __syncthreads();

  const int lane32 = tid & 31;
  const int grp    = tid >> 5;     // 8 groups x 8 rows
#pragma unroll
  for (int rr = 0; rr < 8; ++rr) {
    const int row = grp * 8 + rr;
    int4  o4 = *(const int4*)&soff[row][0];   // broadcast LDS reads
    f32x4 c4 = *(const f32x4*)&scf[row][0];
    f32x4 v0 = *(const f32x4*)(G + o4.x + lane32 * 4);   // L2-hit gathers
    f32x4 v1 = *(const f32x4*)(G + o4.y + lane32 * 4);
    f32x4 v2 = *(const f32x4*)(G + o4.z + lane32 * 4);
    f32x4 v3 = *(const f32x4*)(G + o4.w + lane32 * 4);
    f32x4 acc = c4.x * v0;
    acc += c4.y * v1;
    acc += c4.z * v2;
    acc += c4.w * v3;
    *(f32x4*)(out + (rbase + row) * 128 + lane32 * 4) = acc;
  }
}

extern "C" void kernel_launch(void* const* d_in, const int* in_sizes, int n_in,
                              void* d_out, int out_size, void* d_ws, size_t ws_size,
                              hipStream_t stream) {
  const int*   archs  = (const int*)d_in[0];
  const float* init_e = (const float*)d_in[1];
  const float* op_e   = (const float*)d_in[2];
  const float* wx     = (const float*)d_in[3];
  const float* xb     = (const float*)d_in[4];
  const float* w1     = (const float*)d_in[5];
  const float* w2     = (const float*)d_in[6];

  float* G = (float*)d_ws;   // 1444 * 128 * 4 = 739,328 bytes

  prep_kernel<<<PREP_BLOCKS, 512, 0, stream>>>(init_e, op_e, wx, xb, w1, w2, G);
  main_kernel<<<1024, 256, 0, stream>>>(archs, G, (float*)d_out);
}

// Round 6
// 97.760 us; speedup vs baseline: 1.0760x; 1.0263x over previous
//
#include <hip/hip_runtime.h>

// ---------------------------------------------------------------------------
// GCNArchEmbedder on MI355X — gather-table formulation (final, = v1 @98.3us).
//
// Algebra: out[r] = sum_t cnt_t * relu(X[a_t] + X[b_t]) @ (0.25*W2)
// Only 38 distinct X rows (36 op-pair combos + 2 init rows) -> 38*38 = 1444
// distinct relu-pair rows. Prep precomputes
//     G[q=a*38+b][f] = sum_k 0.25*relu(X[a][k]+X[b][k]) * W2[k][f]
// (1444 x 128 fp32 = 739 KB, L2-resident). Main is a pure 4-way gather +
// weighted sum per row: 134 MB L2 reads (~4us) overlapped with a 32 MB
// L3-absorbed output write (~5us). All fp32 — no bf16/MFMA rounding.
//
// Session lessons baked in:
//  - nontemporal stores REGRESS (+7us): they bypass the 256MB L3; plain
//    stores let L3 absorb the output stream. (v2c measurement)
//  - prep restructures (1024-thr arena, 512-thr 1-pass G) are neutral-to-
//    negative (v3: +2us); 256-thr 2-pass G is the best measured. Keep v1.
// ---------------------------------------------------------------------------

typedef __attribute__((ext_vector_type(4))) float f32x4;

#define NSYM 38
#define NPAIR (NSYM * NSYM)          // 1444
#define G_ROWS_PER_BLOCK 16
#define PREP_BLOCKS ((NPAIR + G_ROWS_PER_BLOCK - 1) / G_ROWS_PER_BLOCK)  // 91

__global__ __launch_bounds__(256) void prep_kernel(
    const float* __restrict__ init_emb,   // 2 x 96
    const float* __restrict__ op_emb,     // 8 x 48 (rows 0..5 used)
    const float* __restrict__ wx,         // 96 x 48
    const float* __restrict__ xb,         // 48
    const float* __restrict__ w1,         // 48 x 128
    const float* __restrict__ w2,         // 128 x 128
    float* __restrict__ G)                // out: 1444 x 128
{
  __shared__ float swx[96 * 48];    // 18 KB
  __shared__ float sw1[48 * 128];   // 24 KB
  __shared__ float smisc[6 * 48 + 2 * 96 + 48];
  __shared__ float sU[14][48];
  __shared__ float sR[14 * 128];    // rows 0..5 = P1', 6..11 = P2, 12..13 = Z
  __shared__ float sV[16][128];     // 0.25*relu(Tx+Ty) for this block's rows

  const int tid = threadIdx.x;
  const int qbase = blockIdx.x * G_ROWS_PER_BLOCK;

  for (int i = tid; i < 96 * 48; i += 256) swx[i] = wx[i];
  for (int i = tid; i < 48 * 128; i += 256) sw1[i] = w1[i];
  for (int i = tid; i < 288; i += 256) smisc[i] = op_emb[i];
  if (tid < 192) smisc[288 + tid] = init_emb[tid];
  if (tid < 48)  smisc[480 + tid] = xb[tid];
  __syncthreads();

  const float* sob   = smisc;
  const float* sinit = smisc + 288;
  const float* sxb   = smisc + 480;

  // U rows: 0..5 = xb + op@Wx[0:48]; 6..11 = op@Wx[48:96]; 12..13 = xb + init@Wx
  for (int idx = tid; idx < 14 * 48; idx += 256) {
    int row = idx / 48, k = idx - row * 48;
    float s;
    if (row < 6) {
      s = sxb[k];
      for (int j = 0; j < 48; ++j) s += sob[row * 48 + j] * swx[j * 48 + k];
    } else if (row < 12) {
      s = 0.f;
      for (int j = 0; j < 48; ++j) s += sob[(row - 6) * 48 + j] * swx[(48 + j) * 48 + k];
    } else {
      s = sxb[k];
      for (int j = 0; j < 96; ++j) s += sinit[(row - 12) * 96 + j] * swx[j * 48 + k];
    }
    sU[row][k] = s;
  }
  __syncthreads();

  // R = U @ W1
  for (int idx = tid; idx < 14 * 128; idx += 256) {
    int row = idx >> 7, f = idx & 127;
    float s = 0.f;
    for (int k = 0; k < 48; ++k) s += sU[row][k] * sw1[k * 128 + f];
    sR[idx] = s;
  }
  __syncthreads();

  // sV[i][f] = 0.25 * relu(T[x][f] + T[y][f]),  q = qbase+i, x=q/38, y=q%38
  // T[s<36] = R[s/6] + R[6 + s%6];  T[36]=R[12], T[37]=R[13]
  for (int idx = tid; idx < 16 * 128; idx += 256) {
    int i = idx >> 7, f = idx & 127;
    int q = qbase + i; if (q > NPAIR - 1) q = NPAIR - 1;   // clamp (store guarded)
    int x = q / NSYM, y = q - x * NSYM;
    float tx, ty;
    if (x < 36) { int o1 = x / 6, o2 = x - o1 * 6; tx = sR[o1 * 128 + f] + sR[(6 + o2) * 128 + f]; }
    else        { tx = sR[(x - 24) * 128 + f]; }
    if (y < 36) { int o1 = y / 6, o2 = y - o1 * 6; ty = sR[o1 * 128 + f] + sR[(6 + o2) * 128 + f]; }
    else        { ty = sR[(y - 24) * 128 + f]; }
    sV[i][f] = 0.25f * fmaxf(tx + ty, 0.f);
  }
  __syncthreads();

  // G rows = sV @ W2. thread -> (slot, f-quad); 2 passes over 16 slots.
  const int fq = tid & 31;        // f = fq*4
  const int slot0 = tid >> 5;     // 0..7
#pragma unroll
  for (int pass = 0; pass < 2; ++pass) {
    const int slot = slot0 + pass * 8;
    f32x4 acc = {0.f, 0.f, 0.f, 0.f};
    const float* w2p = w2 + fq * 4;
    for (int k = 0; k < 128; ++k) {
      f32x4 w = *(const f32x4*)(w2p + k * 128);   // coalesced 512B/wave, L1/L2-hot
      acc += sV[slot][k] * w;                      // LDS broadcast
    }
    const int q = qbase + slot;
    if (q < NPAIR) *(f32x4*)(G + q * 128 + fq * 4) = acc;
  }
}

// Main: per row decode 4 (pair, count) descriptors, then 4 coalesced 512B
// gathers from G + weighted sum + 1 coalesced 512B store (L3-absorbed).
__global__ __launch_bounds__(256, 4) void main_kernel(
    const int* __restrict__ archs,   // 65536 rows x 16 ints (8 prev, 8 op)
    const float* __restrict__ G,     // 1444 x 128
    float* __restrict__ out)         // 65536 x 128 fp32
{
  __shared__ int   soff[64][4];   // float-index of G row * 128
  __shared__ float scf[64][4];

  const int tid = threadIdx.x;
  const int rbase = blockIdx.x * 64;

  if (tid < 64) {
    const int* ar = archs + (rbase + tid) * 16;
    int4 pv0 = *(const int4*)(ar);
    int4 pv1 = *(const int4*)(ar + 4);
    int4 op0 = *(const int4*)(ar + 8);
    int4 op1 = *(const int4*)(ar + 12);

    const int sp0 = op0.x * 6 + op0.y;
    const int sp1 = op0.z * 6 + op0.w;
    const int sp2 = op1.x * 6 + op1.y;
    const int sp3 = op1.z * 6 + op1.w;

    int prev[8] = {pv0.x, pv0.y, pv0.z, pv0.w, pv1.x, pv1.y, pv1.z, pv1.w};
#pragma unroll
    for (int t = 0; t < 4; ++t) {
      int pa = prev[2 * t], pb = prev[2 * t + 1];
      int a = (pa == 0) ? 36 : (pa == 1) ? 37 : (pa == 2) ? sp0
            : (pa == 3) ? sp1 : (pa == 4) ? sp2 : sp3;
      int b = (pb == 0) ? 36 : (pb == 1) ? 37 : (pb == 2) ? sp0
            : (pb == 3) ? sp1 : (pb == 4) ? sp2 : sp3;
      int c = 0;
#pragma unroll
      for (int e = 0; e < 8; ++e) c += (prev[e] == t + 2) ? 1 : 0;
      soff[tid][t] = (a * NSYM + b) * 128;
      scf[tid][t]  = (float)c;
    }
  }
  __syncthreads();

  const int lane32 = tid & 31;
  const int grp    = tid >> 5;     // 8 groups x 8 rows
#pragma unroll
  for (int rr = 0; rr < 8; ++rr) {
    const int row = grp * 8 + rr;
    int4  o4 = *(const int4*)&soff[row][0];   // broadcast LDS reads
    f32x4 c4 = *(const f32x4*)&scf[row][0];
    f32x4 v0 = *(const f32x4*)(G + o4.x + lane32 * 4);   // L2-hit gathers
    f32x4 v1 = *(const f32x4*)(G + o4.y + lane32 * 4);
    f32x4 v2 = *(const f32x4*)(G + o4.z + lane32 * 4);
    f32x4 v3 = *(const f32x4*)(G + o4.w + lane32 * 4);
    f32x4 acc = c4.x * v0;
    acc += c4.y * v1;
    acc += c4.z * v2;
    acc += c4.w * v3;
    *(f32x4*)(out + (rbase + row) * 128 + lane32 * 4) = acc;
  }
}

extern "C" void kernel_launch(void* const* d_in, const int* in_sizes, int n_in,
                              void* d_out, int out_size, void* d_ws, size_t ws_size,
                              hipStream_t stream) {
  const int*   archs  = (const int*)d_in[0];
  const float* init_e = (const float*)d_in[1];
  const float* op_e   = (const float*)d_in[2];
  const float* wx     = (const float*)d_in[3];
  const float* xb     = (const float*)d_in[4];
  const float* w1     = (const float*)d_in[5];
  const float* w2     = (const float*)d_in[6];

  float* G = (float*)d_ws;   // 1444 * 128 * 4 = 739,328 bytes

  prep_kernel<<<PREP_BLOCKS, 256, 0, stream>>>(init_e, op_e, wx, xb, w1, w2, G);
  main_kernel<<<1024, 256, 0, stream>>>(archs, G, (float*)d_out);
}